// Round 1
// baseline (421.348 us; speedup 1.0000x reference)
//
#include <hip/hip_runtime.h>
#include <hip/hip_bf16.h>

#define BB 4
#define TT 2048
#define CC 1024
#define HH 16
#define DD 64
#define MM (BB*TT)   // 8192 rows

typedef unsigned short u16;
typedef __bf16 bf16x8 __attribute__((ext_vector_type(8)));
typedef u16 u16x8 __attribute__((ext_vector_type(8)));
typedef u16 u16x4 __attribute__((ext_vector_type(4)));
typedef float f32x4 __attribute__((ext_vector_type(4)));

__device__ __forceinline__ u16 f2bf(float f) {
  union { float f; unsigned u; } v; v.f = f;
  unsigned u = v.u;
  return (u16)((u + 0x7fffu + ((u >> 16) & 1u)) >> 16);  // RNE
}
__device__ __forceinline__ float bf2f(u16 s) {
  union { unsigned u; float f; } v; v.u = ((unsigned)s) << 16; return v.f;
}
__device__ __forceinline__ bf16x8 ld_bf16x8(const u16* p) {
  return *reinterpret_cast<const bf16x8*>(p);
}
__device__ __forceinline__ f32x4 zero4() {
  f32x4 z; z[0] = 0.f; z[1] = 0.f; z[2] = 0.f; z[3] = 0.f; return z;
}

// ---------------- cast x (fp32 -> bf16), vectorized ----------------
__global__ void k_cast_bf16(const float* __restrict__ x, u16* __restrict__ o, int n4) {
  int i = blockIdx.x * blockDim.x + threadIdx.x;
  if (i >= n4) return;
  const float4 v = reinterpret_cast<const float4*>(x)[i];
  u16x4 r; r.x = f2bf(v.x); r.y = f2bf(v.y); r.z = f2bf(v.z); r.w = f2bf(v.w);
  reinterpret_cast<u16x4*>(o)[i] = r;
}

// ---------------- transpose-cast W [K][N] fp32 -> Wt [N][K] bf16 ----------------
__global__ void k_transpose_bf16(const float* __restrict__ W, u16* __restrict__ Wt,
                                 int K, int N) {
  __shared__ float tile[32][33];
  int nb = blockIdx.x * 32, kb = blockIdx.y * 32;
  int tx = threadIdx.x & 31, ty = threadIdx.x >> 5;  // 256 thr: ty 0..7
  #pragma unroll
  for (int i = ty; i < 32; i += 8)
    tile[i][tx] = W[(size_t)(kb + i) * N + nb + tx];
  __syncthreads();
  #pragma unroll
  for (int i = ty; i < 32; i += 8)
    Wt[(size_t)(nb + i) * K + kb + tx] = f2bf(tile[tx][i]);
}

// ---------------- GEMM  C[M,N] = A[M,K](bf16) * Bt[N,K](bf16)^T ----------------
// 128x128 tile, BK=64, 4 waves in 2x2, each wave 4x4 of 16x16x32 MFMAs.
// LDS XOR swizzle: 16B chunk index ^ (row & 7) -> conflict-minimal staging + frag reads.
// EPI==0: fp32 row-major out.  EPI==1: scatter q->[B,H,T,D], k->[B,H,T,D], v->[B,H,D,T].
template<int EPI>
__global__ __launch_bounds__(256, 2)
void k_gemm_bt(const u16* __restrict__ A, const u16* __restrict__ Bt,
               float* __restrict__ outF, u16* __restrict__ qb, u16* __restrict__ kb,
               u16* __restrict__ vt, int N, int K)
{
  __shared__ u16 As[128 * 64];
  __shared__ u16 Bs[128 * 64];
  const int tid  = threadIdx.x;
  const int lane = tid & 63, w = tid >> 6;
  const int l16  = lane & 15, quad = lane >> 4;
  const int wr = w >> 1, wc = w & 1;
  const int m0 = blockIdx.y * 128, n0 = blockIdx.x * 128;
  const int col8 = tid & 7, row0 = tid >> 3;  // 8 thr/row, 32 rows/pass

  f32x4 acc[4][4];
  #pragma unroll
  for (int i = 0; i < 4; ++i)
    #pragma unroll
    for (int j = 0; j < 4; ++j) acc[i][j] = zero4();

  for (int k0 = 0; k0 < K; k0 += 64) {
    __syncthreads();
    #pragma unroll
    for (int r = row0; r < 128; r += 32) {
      u16x8 va = *reinterpret_cast<const u16x8*>(A  + (size_t)(m0 + r) * K + k0 + col8 * 8);
      *reinterpret_cast<u16x8*>(&As[r * 64 + (col8 ^ (r & 7)) * 8]) = va;
      u16x8 vb = *reinterpret_cast<const u16x8*>(Bt + (size_t)(n0 + r) * K + k0 + col8 * 8);
      *reinterpret_cast<u16x8*>(&Bs[r * 64 + (col8 ^ (r & 7)) * 8]) = vb;
    }
    __syncthreads();
    #pragma unroll
    for (int s = 0; s < 2; ++s) {
      bf16x8 af[4], bfr[4];
      #pragma unroll
      for (int i = 0; i < 4; ++i) {
        int mrow = wr * 64 + i * 16 + l16;
        af[i]  = ld_bf16x8(&As[mrow * 64 + ((s * 4 + quad) ^ (l16 & 7)) * 8]);
        int nrow = wc * 64 + i * 16 + l16;
        bfr[i] = ld_bf16x8(&Bs[nrow * 64 + ((s * 4 + quad) ^ (l16 & 7)) * 8]);
      }
      #pragma unroll
      for (int i = 0; i < 4; ++i)
        #pragma unroll
        for (int j = 0; j < 4; ++j)
          acc[i][j] = __builtin_amdgcn_mfma_f32_16x16x32_bf16(af[i], bfr[j], acc[i][j], 0, 0, 0);
    }
  }

  // epilogue: C/D layout col = lane&15, row = quad*4 + reg (m89-verified)
  #pragma unroll
  for (int i = 0; i < 4; ++i) {
    #pragma unroll
    for (int j = 0; j < 4; ++j) {
      #pragma unroll
      for (int r = 0; r < 4; ++r) {
        int m = m0 + wr * 64 + i * 16 + quad * 4 + r;
        int n = n0 + wc * 64 + j * 16 + l16;
        float v = acc[i][j][r];
        if (EPI == 0) {
          outF[(size_t)m * N + n] = v;
        } else {
          int b = m >> 11, t = m & 2047;  // T = 2048
          u16 bv = f2bf(v);
          if (n < CC) {
            int h = n >> 6, d = n & 63;
            qb[(((size_t)(b * HH + h) * TT + t) << 6) + d] = bv;
          } else if (n < 2 * CC) {
            int n2 = n - CC; int h = n2 >> 6, d = n2 & 63;
            kb[(((size_t)(b * HH + h) * TT + t) << 6) + d] = bv;
          } else {
            int n2 = n - 2 * CC; int h = n2 >> 6, d = n2 & 63;
            vt[((size_t)(b * HH + h) * DD + d) * TT + t] = bv;  // transposed [B,H,D,T]
          }
        }
      }
    }
  }
}

// ---------------- flash attention (causal), 64 q-rows/block, 4 waves x 16 rows ----------------
__global__ __launch_bounds__(256, 2)
void k_attn(const u16* __restrict__ qb, const u16* __restrict__ kb,
            const u16* __restrict__ vt, u16* __restrict__ y)
{
  __shared__ u16 Qs[64 * 64], Ks[64 * 64], Vs[64 * 64], Ps[4 * 16 * 64];
  const int tid  = threadIdx.x;
  const int lane = tid & 63, w = tid >> 6;
  const int l16  = lane & 15, quad = lane >> 4;
  const int col8 = tid & 7, row0 = tid >> 3;

  const int bx = blockIdx.x;
  const int qt = bx & 31, bh = bx >> 5;      // 32 q-tiles; bh = b*16 + h
  const int h  = bh & 15, b = bh >> 4;

  const u16* qptr = qb + ((size_t)bh * TT + qt * 64) * DD;
  const u16* kptr = kb + (size_t)bh * TT * DD;
  const u16* vptr = vt + (size_t)bh * DD * TT;   // [D][T]

  // stage Q once, pre-scaled by 1/sqrt(D) = 0.125 (pow2 -> exact in bf16)
  #pragma unroll
  for (int r = row0; r < 64; r += 32) {
    u16x8 v = *reinterpret_cast<const u16x8*>(qptr + (size_t)r * DD + col8 * 8);
    u16x8 o;
    #pragma unroll
    for (int e = 0; e < 8; ++e) o[e] = f2bf(bf2f(v[e]) * 0.125f);
    *reinterpret_cast<u16x8*>(&Qs[r * 64 + (col8 ^ (r & 7)) * 8]) = o;
  }
  __syncthreads();
  bf16x8 qf[2];
  #pragma unroll
  for (int s = 0; s < 2; ++s)
    qf[s] = ld_bf16x8(&Qs[(w * 16 + l16) * 64 + ((s * 4 + quad) ^ (l16 & 7)) * 8]);

  float mr[4], lr[4];
  f32x4 O[4];
  #pragma unroll
  for (int r = 0; r < 4; ++r) { mr[r] = -__builtin_inff(); lr[r] = 0.f; }
  #pragma unroll
  for (int j = 0; j < 4; ++j) O[j] = zero4();

  for (int kt = 0; kt <= qt; ++kt) {
    __syncthreads();
    #pragma unroll
    for (int r = row0; r < 64; r += 32) {
      u16x8 vk = *reinterpret_cast<const u16x8*>(kptr + (size_t)(kt * 64 + r) * DD + col8 * 8);
      *reinterpret_cast<u16x8*>(&Ks[r * 64 + (col8 ^ (r & 7)) * 8]) = vk;
      u16x8 vv = *reinterpret_cast<const u16x8*>(vptr + (size_t)r * TT + kt * 64 + col8 * 8);
      *reinterpret_cast<u16x8*>(&Vs[r * 64 + (col8 ^ (r & 7)) * 8]) = vv;
    }
    __syncthreads();

    // S = Q Kt^T (already scaled): wave w owns rows w*16..+16, all 64 cols
    f32x4 S[4];
    #pragma unroll
    for (int j = 0; j < 4; ++j) S[j] = zero4();
    #pragma unroll
    for (int s = 0; s < 2; ++s) {
      #pragma unroll
      for (int j = 0; j < 4; ++j) {
        bf16x8 kf = ld_bf16x8(&Ks[(j * 16 + l16) * 64 + ((s * 4 + quad) ^ (l16 & 7)) * 8]);
        S[j] = __builtin_amdgcn_mfma_f32_16x16x32_bf16(qf[s], kf, S[j], 0, 0, 0);
      }
    }
    if (kt == qt) {  // diagonal tile: causal mask (local indices, same 64-range)
      #pragma unroll
      for (int j = 0; j < 4; ++j)
        #pragma unroll
        for (int r = 0; r < 4; ++r) {
          int kg = j * 16 + l16;
          int qg = w * 16 + quad * 4 + r;
          if (kg > qg) S[j][r] = -__builtin_inff();
        }
    }
    // online softmax: row stats live in the 16 lanes of each quad (xor 1,2,4,8 stays in-quad)
    float mt[4];
    #pragma unroll
    for (int r = 0; r < 4; ++r)
      mt[r] = fmaxf(fmaxf(S[0][r], S[1][r]), fmaxf(S[2][r], S[3][r]));
    #pragma unroll
    for (int off = 1; off <= 8; off <<= 1)
      #pragma unroll
      for (int r = 0; r < 4; ++r)
        mt[r] = fmaxf(mt[r], __shfl_xor(mt[r], off));
    float mnew[4], alpha[4], rs[4];
    #pragma unroll
    for (int r = 0; r < 4; ++r) {
      mnew[r]  = fmaxf(mr[r], mt[r]);
      alpha[r] = __expf(mr[r] - mnew[r]);   // exp(-inf)=0 on first tile
      rs[r] = 0.f;
    }
    #pragma unroll
    for (int j = 0; j < 4; ++j)
      #pragma unroll
      for (int r = 0; r < 4; ++r) {
        float p = __expf(S[j][r] - mnew[r]);
        S[j][r] = p;
        rs[r] += p;
      }
    #pragma unroll
    for (int off = 1; off <= 8; off <<= 1)
      #pragma unroll
      for (int r = 0; r < 4; ++r)
        rs[r] += __shfl_xor(rs[r], off);
    #pragma unroll
    for (int r = 0; r < 4; ++r) {
      lr[r] = lr[r] * alpha[r] + rs[r];
      mr[r] = mnew[r];
    }
    #pragma unroll
    for (int j = 0; j < 4; ++j)
      #pragma unroll
      for (int r = 0; r < 4; ++r)
        O[j][r] *= alpha[r];

    // P: C-layout -> LDS (bf16) -> A-layout (wave-private region, no barrier needed)
    #pragma unroll
    for (int j = 0; j < 4; ++j)
      #pragma unroll
      for (int r = 0; r < 4; ++r) {
        int m = quad * 4 + r;
        int col = j * 16 + l16;
        Ps[w * 1024 + m * 64 + ((col >> 3) ^ (m & 7)) * 8 + (col & 7)] = f2bf(S[j][r]);
      }
    #pragma unroll
    for (int s = 0; s < 2; ++s) {
      bf16x8 pf = ld_bf16x8(&Ps[w * 1024 + l16 * 64 + ((s * 4 + quad) ^ (l16 & 7)) * 8]);
      #pragma unroll
      for (int j = 0; j < 4; ++j) {
        bf16x8 vf = ld_bf16x8(&Vs[(j * 16 + l16) * 64 + ((s * 4 + quad) ^ (l16 & 7)) * 8]);
        O[j] = __builtin_amdgcn_mfma_f32_16x16x32_bf16(pf, vf, O[j], 0, 0, 0);
      }
    }
  }

  // epilogue: O /= l, write y [B,T,C] bf16
  #pragma unroll
  for (int j = 0; j < 4; ++j)
    #pragma unroll
    for (int r = 0; r < 4; ++r) {
      int t  = qt * 64 + w * 16 + quad * 4 + r;
      int ch = h * 64 + j * 16 + l16;
      float val = O[j][r] / lr[r];
      y[(size_t)(b * TT + t) * CC + ch] = f2bf(val);
    }
}

extern "C" void kernel_launch(void* const* d_in, const int* in_sizes, int n_in,
                              void* d_out, int out_size, void* d_ws, size_t ws_size,
                              hipStream_t stream) {
  const float* x  = (const float*)d_in[0];   // [B,T,C]
  const float* Wa = (const float*)d_in[1];   // [C,3C]
  const float* Wp = (const float*)d_in[2];   // [C,C]
  float* out = (float*)d_out;                // [B,T,C] fp32

  // workspace layout (bf16/u16 elems), total ~92.3 MB
  u16* ws   = (u16*)d_ws;
  u16* xb   = ws;                             // M*C        = 8388608
  u16* Wab  = xb   + (size_t)MM * CC;         // 3C*C (W_attn^T) = 3145728
  u16* Wpb  = Wab  + (size_t)3 * CC * CC;     // C*C  (W_proj^T) = 1048576
  u16* qbuf = Wpb  + (size_t)CC * CC;         // [B,H,T,D]  = 8388608
  u16* kbuf = qbuf + (size_t)MM * CC;         // [B,H,T,D]
  u16* vtb  = kbuf + (size_t)MM * CC;         // [B,H,D,T]
  u16* yb   = vtb  + (size_t)MM * CC;         // [B,T,C]

  k_cast_bf16<<<(MM * CC / 4) / 256, 256, 0, stream>>>(x, xb, MM * CC / 4);
  k_transpose_bf16<<<dim3(3 * CC / 32, CC / 32), 256, 0, stream>>>(Wa, Wab, CC, 3 * CC);
  k_transpose_bf16<<<dim3(CC / 32, CC / 32), 256, 0, stream>>>(Wp, Wpb, CC, CC);
  k_gemm_bt<1><<<dim3(3 * CC / 128, MM / 128), 256, 0, stream>>>(
      xb, Wab, nullptr, qbuf, kbuf, vtb, 3 * CC, CC);
  k_attn<<<BB * HH * (TT / 64), 256, 0, stream>>>(qbuf, kbuf, vtb, yb);
  k_gemm_bt<0><<<dim3(CC / 128, MM / 128), 256, 0, stream>>>(
      yb, Wpb, out, nullptr, nullptr, nullptr, CC, CC);
}